// Round 3
// baseline (180.049 us; speedup 1.0000x reference)
//
#include <hip/hip_runtime.h>

#define BIG 1e8f
#define LN2 0.69314718f
// band quantization: q = round(dist * QENC), dist_log2 = q * DDEC
#define QENC 1.7686573f   /* log2(e) * 255/208 */
#define DDEC 0.81568627f  /* 208/255 (log2 units) */

#define NSLOT 10
#define BROW 264          /* band row stride, bytes (16 cols pad -> 2-way free) */
#define BSTRIPE (16 * BROW)

typedef _Float16 half8 __attribute__((ext_vector_type(8)));
typedef float f32x4 __attribute__((ext_vector_type(4)));

__device__ __forceinline__ float exp2g(float x) {
#if __has_builtin(__builtin_amdgcn_exp2f)
    return __builtin_amdgcn_exp2f(x);
#else
    return exp2f(x);
#endif
}
__device__ __forceinline__ float log2g(float x) {
#if __has_builtin(__builtin_amdgcn_logf)
    return __builtin_amdgcn_logf(x);
#else
    return log2f(x);
#endif
}

// base-2 softmin of {precomputed pair (m = min, s = 2^(m-p)+2^(m-q)), v}
__device__ __forceinline__ float smp(float m, float s, float v) {
    float mn = fminf(m, v);
    return mn - log2g(exp2g(mn - v) + s * exp2g(mn - m));
}

// Produce 2 MFMA tiles (ci0, ci0+1) of stripe sg into the u8 LDS ring.
// Transposed product: A = y rows (tile ci), B = x stripe rows. Lane l holds
// D[m = (l>>4)*4+reg][n = l&15] = dot(y[ci*16+m], x[rbase+n]) -> 4 consecutive
// y-cols of one x-row -> one packed ds_write_b32.
__device__ __forceinline__ void produce_tiles(int sg, int ci0, int tid,
                                              const _Float16* xh,
                                              const float* x2s,
                                              const float* y2s,
                                              unsigned char* band,
                                              const half8* yfrag) {
    const int rbase = sg * 16;
    const half8 bfrag = *(const half8*)&xh[(rbase + (tid & 15)) * 32 + (tid >> 4) * 8];
    unsigned char* bs = band + (sg % NSLOT) * BSTRIPE;
    const float xx = x2s[rbase + (tid & 15)];
    const int qd = tid >> 4;
    const int xr = tid & 15;
#pragma unroll
    for (int u = 0; u < 2; u++) {
        const int ci = ci0 + u;
        f32x4 acc = {0.f, 0.f, 0.f, 0.f};
        acc = __builtin_amdgcn_mfma_f32_16x16x32_f16(yfrag[ci], bfrag, acc, 0, 0, 0);
        const float4 yy = *(const float4*)&y2s[ci * 16 + qd * 4];
        float dv;
        unsigned int pk;
        dv = fminf(fmaxf(fmaf(-2.f, acc[0], xx + yy.x), 0.f) * QENC, 254.9f);
        pk = (unsigned int)(dv + 0.5f);
        dv = fminf(fmaxf(fmaf(-2.f, acc[1], xx + yy.y), 0.f) * QENC, 254.9f);
        pk |= (unsigned int)(dv + 0.5f) << 8;
        dv = fminf(fmaxf(fmaf(-2.f, acc[2], xx + yy.z), 0.f) * QENC, 254.9f);
        pk |= (unsigned int)(dv + 0.5f) << 16;
        dv = fminf(fmaxf(fmaf(-2.f, acc[3], xx + yy.w), 0.f) * QENC, 254.9f);
        pk |= (unsigned int)(dv + 0.5f) << 24;
        *(unsigned int*)&bs[xr * BROW + ci * 16 + qd * 4] = pk;
    }
}

// One block = one batch = ONE wave. Thread t owns columns 4t+1..4t+4.
// 2-row supersteps: at superstep s, lane t computes rows rA=2(s-t)-1, rB=rA+1.
// Critical path 5 softmins / 2 rows; 3 shfls / 2 rows; no barriers in loop.
__global__ __launch_bounds__(64, 1) void sdtw_kernel(
    const float* __restrict__ x, const float* __restrict__ y,
    float* __restrict__ out) {
    __shared__ __align__(16) _Float16 xh[256 * 32];           // 16 KB
    __shared__ float x2s[256];
    __shared__ float y2s[256];
    __shared__ __align__(16) unsigned char band[NSLOT * BSTRIPE];  // 42240 B

    const int tid = threadIdx.x;
    const int b = blockIdx.x;
    const float* xb = x + (size_t)b * 8192;
    const float* yb = y + (size_t)b * 8192;

    // ---- stage x as f16 + norms (4 rows/lane) ----
    for (int rr = 0; rr < 4; rr++) {
        const int r = tid + rr * 64;
        const float4* px = (const float4*)(xb + r * 32);
        union { _Float16 h[32]; half8 v[4]; } uc;
        float s2 = 0.f;
#pragma unroll
        for (int q = 0; q < 8; q++) {
            float4 f = px[q];
            s2 += f.x * f.x + f.y * f.y + f.z * f.z + f.w * f.w;
            uc.h[4 * q + 0] = (_Float16)f.x;
            uc.h[4 * q + 1] = (_Float16)f.y;
            uc.h[4 * q + 2] = (_Float16)f.z;
            uc.h[4 * q + 3] = (_Float16)f.w;
        }
        half8* dst = (half8*)&xh[r * 32];
#pragma unroll
        for (int q = 0; q < 4; q++) dst[q] = uc.v[q];
        x2s[r] = s2;

        const float4* py = (const float4*)(yb + r * 32);
        float t2 = 0.f;
#pragma unroll
        for (int q = 0; q < 8; q++) {
            float4 f = py[q];
            t2 += f.x * f.x + f.y * f.y + f.z * f.z + f.w * f.w;
        }
        y2s[r] = t2;
    }

    half8 yfrag[16];  // lane l: y[ci*16 + (l&15)][(l>>4)*8 + j]
#pragma unroll
    for (int ci = 0; ci < 16; ci++) {
        const float* yp = yb + (ci * 16 + (tid & 15)) * 32 + (tid >> 4) * 8;
        float4 f0 = *(const float4*)yp;
        float4 f1 = *(const float4*)(yp + 4);
        half8 v;
        v[0] = (_Float16)f0.x; v[1] = (_Float16)f0.y;
        v[2] = (_Float16)f0.z; v[3] = (_Float16)f0.w;
        v[4] = (_Float16)f1.x; v[5] = (_Float16)f1.y;
        v[6] = (_Float16)f1.z; v[7] = (_Float16)f1.w;
        yfrag[ci] = v;
    }
    __syncthreads();

    // ---- prologue: stripes 0,1 ----
    for (int ci0 = 0; ci0 < 16; ci0 += 2) {
        produce_tiles(0, ci0, tid, xh, x2s, y2s, band, yfrag);
        produce_tiles(1, ci0, tid, xh, x2s, y2s, band, yfrag);
    }
    __syncthreads();

    // ---- DP state (log2 domain): u_j = D[rA-1][c_j]; boundary relays ----
    float u0 = BIG, u1 = BIG, u2 = BIG, u3 = BIG;
    float pA3 = BIG, pB3 = BIG, ppB3 = BIG;

    for (int s = 1; s <= 191; s++) {
        // shfls first: their LDS latency overlaps the decode/pair work below
        float L0 = __shfl_up(pA3, 1);  // D[rA][c0-1]
        float L1 = __shfl_up(pB3, 1);  // D[rB][c0-1]
        float G0 = __shfl_up(ppB3, 1); // D[rA-1][c0-1]
        if (tid == 0) {
            L0 = BIG;
            L1 = BIG;
            G0 = (s == 1) ? 0.f : BIG;
        }

        // spread production: 2 tiles of stripe sg per superstep over 8 steps
        {
            const int sg = (s >> 3) + 1;
            if (sg >= 2 && sg <= 15)
                produce_tiles(sg, (s & 7) * 2, tid, xh, x2s, y2s, band, yfrag);
        }

        const int rA = 2 * (s - tid) - 1;
        const bool act = (rA >= 1) && (rA <= 255);
        int ra = rA < 1 ? 1 : (rA > 255 ? 255 : rA);
        const int r0a = ra - 1, r0b = ra;  // 0-based rows
        const unsigned int wa = *(const unsigned int*)&band[((r0a >> 4) % NSLOT) * BSTRIPE + (r0a & 15) * BROW + (tid << 2)];
        const unsigned int wb = *(const unsigned int*)&band[((r0b >> 4) % NSLOT) * BSTRIPE + (r0b & 15) * BROW + (tid << 2)];
        const float dA0 = (float)(wa & 255u) * DDEC;
        const float dA1 = (float)((wa >> 8) & 255u) * DDEC;
        const float dA2 = (float)((wa >> 16) & 255u) * DDEC;
        const float dA3 = (float)(wa >> 24) * DDEC;
        const float dB0 = (float)(wb & 255u) * DDEC;
        const float dB1 = (float)((wb >> 8) & 255u) * DDEC;
        const float dB2 = (float)((wb >> 16) & 255u) * DDEC;
        const float dB3 = (float)(wb >> 24) * DDEC;

        // A-row pair precomputes (off the critical chain, except m0 needs G0)
        const float m1 = fminf(u1, u0), s1 = exp2g(m1 - u1) + exp2g(m1 - u0);
        const float m2 = fminf(u2, u1), s2 = exp2g(m2 - u2) + exp2g(m2 - u1);
        const float m3 = fminf(u3, u2), s3 = exp2g(m3 - u3) + exp2g(m3 - u2);
        const float m0 = fminf(u0, G0), s0 = exp2g(m0 - u0) + exp2g(m0 - G0);

        // A-row chain: A_j = dA_j + softmin(u_j, A_{j-1}, u_{j-1})
        const float A0 = dA0 + smp(m0, s0, L0);
        const float A1 = dA1 + smp(m1, s1, A0);
        const float A2 = dA2 + smp(m2, s2, A1);
        const float A3 = dA3 + smp(m3, s3, A2);

        // B-row pairs (computed as A's emerge; overlap with chain)
        const float n0 = fminf(A0, L0), t0 = exp2g(n0 - A0) + exp2g(n0 - L0);
        const float n1 = fminf(A1, A0), t1 = exp2g(n1 - A1) + exp2g(n1 - A0);
        const float n2 = fminf(A2, A1), t2 = exp2g(n2 - A2) + exp2g(n2 - A1);
        const float n3 = fminf(A3, A2), t3 = exp2g(n3 - A3) + exp2g(n3 - A2);

        // B-row chain: B_j = dB_j + softmin(A_j, B_{j-1}, A_{j-1})
        const float B0 = dB0 + smp(n0, t0, L1);
        const float B1 = dB1 + smp(n1, t1, B0);
        const float B2 = dB2 + smp(n2, t2, B1);
        const float B3 = dB3 + smp(n3, t3, B2);

        if (act) {
            u0 = B0; u1 = B1; u2 = B2; u3 = B3;
            ppB3 = pB3;
            pB3 = B3;
            pA3 = A3;
        }
    }

    if (tid == 63) atomicAdd(out, u3 * (LN2 / 256.f));  // D[256][256] -> mean
}

extern "C" void kernel_launch(void* const* d_in, const int* in_sizes, int n_in,
                              void* d_out, int out_size, void* d_ws, size_t ws_size,
                              hipStream_t stream) {
    const float* x = (const float*)d_in[0];
    const float* y = (const float*)d_in[1];
    float* out = (float*)d_out;
    const int B = in_sizes[0] / (256 * 32);  // 256

    hipMemsetAsync(d_out, 0, sizeof(float), stream);
    sdtw_kernel<<<dim3(B), dim3(64), 0, stream>>>(x, y, out);
}

// Round 4
// 158.996 us; speedup vs baseline: 1.1324x; 1.1324x over previous
//
#include <hip/hip_runtime.h>

#define BIG 1e8f
#define LN2 0.69314718f
// band quantization: q = round(dist * QENC), dist_log2 = q * DDEC
#define QENC 1.7686573f   /* log2(e) * 255/208 */
#define DDEC 0.81568627f  /* 208/255 (log2 units) */

#define NSLOT 10
#define BROW 264          /* band row stride, bytes */
#define BSTRIPE (16 * BROW)

typedef _Float16 half8 __attribute__((ext_vector_type(8)));
typedef float f32x4 __attribute__((ext_vector_type(4)));

__device__ __forceinline__ float exp2g(float x) {
#if __has_builtin(__builtin_amdgcn_exp2f)
    return __builtin_amdgcn_exp2f(x);
#else
    return exp2f(x);
#endif
}
__device__ __forceinline__ float log2g(float x) {
#if __has_builtin(__builtin_amdgcn_logf)
    return __builtin_amdgcn_logf(x);
#else
    return log2f(x);
#endif
}

// pair precompute: m = min(a,b), s = 2^(m-a) + 2^(m-b) = 1 + 2^(-|a-b|)
__device__ __forceinline__ void pairp(float a, float b, float& m, float& s) {
    m = fminf(a, b);
    s = exp2g(-fabsf(a - b)) + 1.f;
}
// softmin of {pair (m,s), v}: mn - log2(2^(mn-v) + s*2^(mn-m)); one of the
// exps is 2^0=1, so compute t = 2^(-|v-m|) and select.
__device__ __forceinline__ float smp(float m, float s, float v) {
    float d = v - m;
    float t = exp2g(-fabsf(d));          // -|d| folds into exp input modifier
    float r = (d > 0.f) ? (t + s) : fmaf(s, t, 1.f);
    return fminf(m, v) - log2g(r);
}

// whole-wave shift-up-by-1 via DPP wave_shr:1 (pure VALU, ~8 cyc vs ~120 for
// ds_bpermute). Lane 0 (invalid source, bound_ctrl=0) receives `oldv`.
__device__ __forceinline__ float shfl_up1(float v, float oldv) {
    int r = __builtin_amdgcn_update_dpp(
        __builtin_bit_cast(int, oldv), __builtin_bit_cast(int, v),
        0x138 /*wave_shr:1*/, 0xf, 0xf, false);
    return __builtin_bit_cast(float, r);
}

__device__ __forceinline__ unsigned int pack_d(f32x4 acc, float xx, float4 yy) {
    float dv;
    unsigned int pk;
    dv = fminf(fmaxf(fmaf(-2.f, acc[0], xx + yy.x), 0.f) * QENC, 254.9f);
    pk = (unsigned int)(dv + 0.5f);
    dv = fminf(fmaxf(fmaf(-2.f, acc[1], xx + yy.y), 0.f) * QENC, 254.9f);
    pk |= (unsigned int)(dv + 0.5f) << 8;
    dv = fminf(fmaxf(fmaf(-2.f, acc[2], xx + yy.z), 0.f) * QENC, 254.9f);
    pk |= (unsigned int)(dv + 0.5f) << 16;
    dv = fminf(fmaxf(fmaf(-2.f, acc[3], xx + yy.w), 0.f) * QENC, 254.9f);
    pk |= (unsigned int)(dv + 0.5f) << 24;
    return pk;
}

// One block = one batch = ONE wave. Lane t owns columns 4t+1..4t+4 (1-based).
// 2-row supersteps s=0..191: lane t computes rows rA=2(s-t)-1, rB=rA+1.
// Cross-lane relay via DPP (no LDS on the chain); G0(s) = L1(s-1) identity
// removes the third shuffle. Band words software-pipelined one superstep
// ahead. Distance stripes MFMA-produced into a 10-slot u8 LDS ring; the inner
// 8-fold unroll makes the produced tile index static so yfrag stays in VGPRs.
__global__ __launch_bounds__(64, 1) void sdtw_kernel(
    const float* __restrict__ x, const float* __restrict__ y,
    float* __restrict__ out) {
    __shared__ __align__(16) _Float16 xh[256 * 32];                // 16 KB
    __shared__ float x2s[256];
    __shared__ float y2s[256];
    __shared__ __align__(16) unsigned char band[NSLOT * BSTRIPE];  // 42240 B

    const int tid = threadIdx.x;
    const int b = blockIdx.x;
    const float* xb = x + (size_t)b * 8192;
    const float* yb = y + (size_t)b * 8192;

    // ---- stage x as f16 + norms (4 rows/lane); y norms ----
    for (int rr = 0; rr < 4; rr++) {
        const int r = tid + rr * 64;
        const float4* px = (const float4*)(xb + r * 32);
        union { _Float16 h[32]; half8 v[4]; } uc;
        float s2 = 0.f;
#pragma unroll
        for (int q = 0; q < 8; q++) {
            float4 f = px[q];
            s2 += f.x * f.x + f.y * f.y + f.z * f.z + f.w * f.w;
            uc.h[4 * q + 0] = (_Float16)f.x;
            uc.h[4 * q + 1] = (_Float16)f.y;
            uc.h[4 * q + 2] = (_Float16)f.z;
            uc.h[4 * q + 3] = (_Float16)f.w;
        }
        half8* dst = (half8*)&xh[r * 32];
#pragma unroll
        for (int q = 0; q < 4; q++) dst[q] = uc.v[q];
        x2s[r] = s2;

        const float4* py = (const float4*)(yb + r * 32);
        float t2 = 0.f;
#pragma unroll
        for (int q = 0; q < 8; q++) {
            float4 f = py[q];
            t2 += f.x * f.x + f.y * f.y + f.z * f.z + f.w * f.w;
        }
        y2s[r] = t2;
    }

    half8 yfrag[16];  // A-frags (static-indexed ONLY -> stays in VGPRs)
#pragma unroll
    for (int ci = 0; ci < 16; ci++) {
        const float* yp = yb + (ci * 16 + (tid & 15)) * 32 + (tid >> 4) * 8;
        float4 f0 = *(const float4*)yp;
        float4 f1 = *(const float4*)(yp + 4);
        half8 v;
        v[0] = (_Float16)f0.x; v[1] = (_Float16)f0.y;
        v[2] = (_Float16)f0.z; v[3] = (_Float16)f0.w;
        v[4] = (_Float16)f1.x; v[5] = (_Float16)f1.y;
        v[6] = (_Float16)f1.z; v[7] = (_Float16)f1.w;
        yfrag[ci] = v;
    }
    __syncthreads();

    // ---- prologue: produce stripes 0,1 (static ci unroll) ----
    const int qd = tid >> 4, xr = tid & 15;
    for (int sg = 0; sg < 2; sg++) {
        const half8 bf = *(const half8*)&xh[(sg * 16 + xr) * 32 + qd * 8];
        const float xx0 = x2s[sg * 16 + xr];
        unsigned char* bs = band + sg * BSTRIPE;
#pragma unroll
        for (int ci = 0; ci < 16; ci++) {
            f32x4 acc = {0.f, 0.f, 0.f, 0.f};
            acc = __builtin_amdgcn_mfma_f32_16x16x32_f16(yfrag[ci], bf, acc, 0, 0, 0);
            const float4 yy = *(const float4*)&y2s[ci * 16 + qd * 4];
            *(unsigned int*)&bs[xr * BROW + ci * 16 + qd * 4] = pack_d(acc, xx0, yy);
        }
    }
    __syncthreads();

    // ---- DP state (log2 domain) ----
    float u0 = BIG, u1 = BIG, u2 = BIG, u3 = BIG;
    float pA3 = BIG, pB3 = BIG;
    float G0 = (tid == 0) ? 0.f : BIG;   // D[0][c0-1]
    unsigned int wa = 0, wb = 0;         // band words for current superstep
    half8 bfragCur = {};                 // stripe B-frag (reloaded at k==7)
    float xxCur = 0.f;

    for (int s8 = 0; s8 < 24; s8++) {
        const bool doprod = (s8 >= 1) && (s8 <= 14);   // stripe sg = s8+1
        const int slotW = ((s8 + 1) >= NSLOT) ? (s8 + 1 - NSLOT) : (s8 + 1);
        unsigned char* bs = band + slotW * BSTRIPE;
#pragma unroll
        for (int k = 0; k < 8; k++) {
            const int s = 8 * s8 + k;

            // chain head: cross-lane relay, pure VALU
            const float L0 = shfl_up1(pA3, BIG);  // D[rA][c0-1]
            const float L1 = shfl_up1(pB3, BIG);  // D[rB][c0-1]

            // production MFMAs (bfrag/yfrag in regs; result used after chain)
            f32x4 acc0 = {0.f, 0.f, 0.f, 0.f}, acc1 = {0.f, 0.f, 0.f, 0.f};
            if (doprod) {
                acc0 = __builtin_amdgcn_mfma_f32_16x16x32_f16(yfrag[2 * k], bfragCur, acc0, 0, 0, 0);
                acc1 = __builtin_amdgcn_mfma_f32_16x16x32_f16(yfrag[2 * k + 1], bfragCur, acc1, 0, 0, 0);
            }

            // off-chain: pairs (G0, u* all ready) + band decode (wa/wb in regs)
            float m0, s0v, m1, s1v, m2, s2v, m3, s3v;
            pairp(u0, G0, m0, s0v);
            pairp(u1, u0, m1, s1v);
            pairp(u2, u1, m2, s2v);
            pairp(u3, u2, m3, s3v);
            const float dA0 = (float)(wa & 255u) * DDEC;
            const float dA1 = (float)((wa >> 8) & 255u) * DDEC;
            const float dA2 = (float)((wa >> 16) & 255u) * DDEC;
            const float dA3 = (float)(wa >> 24) * DDEC;
            const float dB0 = (float)(wb & 255u) * DDEC;
            const float dB1 = (float)((wb >> 8) & 255u) * DDEC;
            const float dB2 = (float)((wb >> 16) & 255u) * DDEC;
            const float dB3 = (float)(wb >> 24) * DDEC;

            // A-row chain
            const float A0 = dA0 + smp(m0, s0v, L0);
            const float A1 = dA1 + smp(m1, s1v, A0);
            const float A2 = dA2 + smp(m2, s2v, A1);
            const float A3 = dA3 + smp(m3, s3v, A2);

            // prefetch next superstep's band words (used next iter -> slack)
            int rna = 2 * s - 2 * tid;
            rna = rna < 0 ? 0 : (rna > 255 ? 255 : rna);
            int rnb = rna + 1;
            rnb = rnb > 255 ? 255 : rnb;
            int sta = rna >> 4; sta = sta >= NSLOT ? sta - NSLOT : sta;
            int stb = rnb >> 4; stb = stb >= NSLOT ? stb - NSLOT : stb;
            const unsigned int waN = *(const unsigned int*)&band[sta * BSTRIPE + (rna & 15) * BROW + (tid << 2)];
            const unsigned int wbN = *(const unsigned int*)&band[stb * BSTRIPE + (rnb & 15) * BROW + (tid << 2)];

            // B-row pairs + chain
            float n0, t0v, n1, t1v, n2, t2v, n3, t3v;
            pairp(A0, L0, n0, t0v);
            pairp(A1, A0, n1, t1v);
            pairp(A2, A1, n2, t2v);
            pairp(A3, A2, n3, t3v);
            const float B0 = dB0 + smp(n0, t0v, L1);
            const float B1 = dB1 + smp(n1, t1v, B0);
            const float B2 = dB2 + smp(n2, t2v, B1);
            const float B3 = dB3 + smp(n3, t3v, B2);

            // production pack + writes (off-chain)
            if (doprod) {
                const float4 yy0 = *(const float4*)&y2s[(2 * k) * 16 + qd * 4];
                const float4 yy1 = *(const float4*)&y2s[(2 * k + 1) * 16 + qd * 4];
                *(unsigned int*)&bs[xr * BROW + (2 * k) * 16 + qd * 4] = pack_d(acc0, xxCur, yy0);
                *(unsigned int*)&bs[xr * BROW + (2 * k + 1) * 16 + qd * 4] = pack_d(acc1, xxCur, yy1);
            }

            // per-stripe B-frag reload (loop-invariant for next 8 supersteps)
            if (k == 7 && s8 <= 13) {
                const int rb = (s8 + 2) * 16 + xr;
                bfragCur = *(const half8*)&xh[rb * 32 + qd * 8];
                xxCur = x2s[rb];
            }

            // state update
            const int rA = 2 * (s - tid) - 1;
            const bool act = (rA >= 1) && (rA <= 255);
            u0 = act ? B0 : u0;
            u1 = act ? B1 : u1;
            u2 = act ? B2 : u2;
            u3 = act ? B3 : u3;
            pA3 = act ? A3 : pA3;
            pB3 = act ? B3 : pB3;
            if (k != 0 || s8 != 0) G0 = L1;  // G0(s+1) = L1(s); keep init at s=0
            wa = waN;
            wb = wbN;
        }
    }

    if (tid == 63) atomicAdd(out, u3 * (LN2 / 256.f));  // D[256][256] -> mean
}

extern "C" void kernel_launch(void* const* d_in, const int* in_sizes, int n_in,
                              void* d_out, int out_size, void* d_ws, size_t ws_size,
                              hipStream_t stream) {
    const float* x = (const float*)d_in[0];
    const float* y = (const float*)d_in[1];
    float* out = (float*)d_out;
    const int B = in_sizes[0] / (256 * 32);  // 256

    hipMemsetAsync(d_out, 0, sizeof(float), stream);
    sdtw_kernel<<<dim3(B), dim3(64), 0, stream>>>(x, y, out);
}